// Round 2
// baseline (786.180 us; speedup 1.0000x reference)
//
#include <hip/hip_runtime.h>
#include <hip/hip_bf16.h>
#include <math.h>

#define NN 8
#define TT 8
#define CC 128
#define HH 64
#define WW 64
#define HW 4096

// ---------------- K1: M[n,t,c] = mean_hw(x) + max_hw(x) -------------------
// one wave (64 threads) per (n,t,c) plane of 4096 fp32 elements
__global__ __launch_bounds__(64) void k1_M(const float* __restrict__ x, float* __restrict__ M){
    int plane = blockIdx.x;               // (n*TT + t)*CC + c
    int lane  = threadIdx.x;              // 0..63
    const float* p = x + (size_t)plane * HW;
    float s = 0.f, mx = -INFINITY;
    #pragma unroll
    for (int it = 0; it < 16; ++it){
        float4 v = *(const float4*)(p + it*256 + lane*4);
        s += v.x + v.y + v.z + v.w;
        mx = fmaxf(mx, fmaxf(fmaxf(v.x, v.y), fmaxf(v.z, v.w)));
    }
    #pragma unroll
    for (int off = 32; off > 0; off >>= 1){
        s += __shfl_xor(s, off, 64);
        mx = fmaxf(mx, __shfl_xor(mx, off, 64));
    }
    if (lane == 0) M[plane] = s * (1.0f/(float)HW) + mx;
}

// ---------------- K2: imp[t,c] = XOR of unioned top-k masks ---------------
// rank = #{v > mine} + #{v == mine with lower index}  (lax.top_k tie rule)
__global__ __launch_bounds__(128) void k2_imp(const float* __restrict__ M, float* __restrict__ imp){
    int t = blockIdx.x;       // 0..7
    int c = threadIdx.x;      // 0..127
    __shared__ float Ms[NN*CC];
    for (int n = 0; n < NN; ++n)
        Ms[n*CC + c] = M[(n*TT + t)*CC + c];
    __syncthreads();
    bool sel_ch = false;
    for (int n = 0; n < NN; ++n){
        float mv = Ms[n*CC + c];
        int rank = 0;
        for (int c2 = 0; c2 < CC; ++c2){
            float v2 = Ms[n*CC + c2];
            rank += (v2 > mv) || (v2 == mv && c2 < c);
        }
        sel_ch = sel_ch || (rank < 64);   // kc = 64
    }
    bool sel_tm = false;
    for (int n = 0; n < NN; ++n){
        float mv = M[(n*TT + t)*CC + c];
        int rank = 0;
        for (int t2 = 0; t2 < TT; ++t2){
            float v2 = M[(n*TT + t2)*CC + c];
            rank += (v2 > mv) || (v2 == mv && t2 < t);
        }
        sel_tm = sel_tm || (rank < 4);    // kt = 4
    }
    imp[t*CC + c] = (sel_ch != sel_tm) ? 1.0f : 0.0f;
}

// ---------------- K3: channel stats + 3x3 conv + sigmoid -> maps ----------
// one block per (n,t) plane; stats staged in 64KB LDS
__global__ __launch_bounds__(512) void k3_maps(
        const float* __restrict__ x, const float* __restrict__ imp,
        const float* __restrict__ w1, const float* __restrict__ w2,
        float* __restrict__ maps){
    int nt  = blockIdx.x;          // n*TT + t
    int t   = nt & (TT-1);
    int tid = threadIdx.x;         // 0..511
    __shared__ float st[4][HW];    // im_avg, im_max, sub_avg, sub_max (64 KB)
    const float* xp = x + (size_t)nt * CC * HW;

    float sa[8], ma[8], sb[8], mb[8];
    #pragma unroll
    for (int k = 0; k < 8; ++k){ sa[k]=0.f; sb[k]=0.f; ma[k]=-INFINITY; mb[k]=-INFINITY; }
    int pos0 = tid * 8;
    for (int c = 0; c < CC; ++c){
        float ip = imp[t*CC + c];
        float4 v0 = *(const float4*)(xp + c*HW + pos0);
        float4 v1 = *(const float4*)(xp + c*HW + pos0 + 4);
        float f[8] = {v0.x, v0.y, v0.z, v0.w, v1.x, v1.y, v1.z, v1.w};
        #pragma unroll
        for (int k = 0; k < 8; ++k){
            float a = ip * f[k];
            float b = f[k] - a;
            sa[k] += a; sb[k] += b;
            ma[k] = fmaxf(ma[k], a);
            mb[k] = fmaxf(mb[k], b);
        }
    }
    #pragma unroll
    for (int k = 0; k < 8; ++k){
        st[0][pos0+k] = sa[k] * (1.0f/64.0f);   // mean/128 / 0.5
        st[1][pos0+k] = ma[k];
        st[2][pos0+k] = sb[k] * (1.0f/64.0f);
        st[3][pos0+k] = mb[k];
    }
    __syncthreads();

    float w1f[18], w2f[18];
    #pragma unroll
    for (int i = 0; i < 18; ++i){ w1f[i] = w1[i]; w2f[i] = w2[i]; }
    float* mp = maps + (size_t)nt * 2 * HW;
    for (int k = 0; k < 8; ++k){
        int pos = pos0 + k;
        int y = pos >> 6, xx = pos & 63;
        float zi = 0.f, zs = 0.f;
        #pragma unroll
        for (int dy = 0; dy < 3; ++dy){
            int yy = y + dy - 1;
            if (yy < 0 || yy >= HH) continue;
            #pragma unroll
            for (int dx = 0; dx < 3; ++dx){
                int xw = xx + dx - 1;
                if (xw < 0 || xw >= WW) continue;
                int sp = yy*WW + xw;
                zi += w1f[dy*3+dx] * st[0][sp] + w1f[9 + dy*3+dx] * st[1][sp];
                zs += w2f[dy*3+dx] * st[2][sp] + w2f[9 + dy*3+dx] * st[3][sp];
            }
        }
        mp[pos]      = 1.0f / (1.0f + expf(-zi));
        mp[HW + pos] = 1.0f / (1.0f + expf(-zs));
    }
}

// ---------------- K5: fused 3D conv over htsa ------------------------------
// out[n,o,c,y,x] = sum_t sum_taps w1[o,t,tap]*a + w2[o,t,tap]*b
// a = im_map*imp*x, b = sub_map*(1-imp)*x, staged per-t in LDS
#define CT 4
#define YT 4
__global__ __launch_bounds__(256) void k5_conv3d(
        const float* __restrict__ x, const float* __restrict__ imp,
        const float* __restrict__ wlast, const float* __restrict__ maps,
        float* __restrict__ out){
    __shared__ float wl[2*TT*27*8];     // [half][t][tap][o]  (13.5 KB)
    __shared__ float la[6*6*66];        // (9.3 KB)
    __shared__ float lb[6*6*66];        // (9.3 KB)
    __shared__ float lm[2*6*66];        // (3.1 KB)
    int tid = threadIdx.x;
    int xl = tid & 63;
    int yl = tid >> 6;                  // 0..3
    int c0 = blockIdx.x * CT;
    int y0 = blockIdx.y * YT;
    int n  = blockIdx.z;

    // stage weights:  wl[(half*216 + t*27 + tap)*8 + o] = wlast[(o*16 + t + 8*half)*27 + tap]
    for (int idx = tid; idx < 2*TT*27*8; idx += 256){
        int o    = idx & 7;
        int r    = idx >> 3;       // half*216 + t*27 + tap
        int half = r / 216;
        int r2   = r % 216;
        int t    = r2 / 27;
        int tap  = r2 % 27;
        wl[idx] = wlast[(o*16 + t + half*8)*27 + tap];
    }

    float acc[8][CT];
    #pragma unroll
    for (int o = 0; o < 8; ++o)
        #pragma unroll
        for (int cl = 0; cl < CT; ++cl) acc[o][cl] = 0.f;

    for (int t = 0; t < TT; ++t){
        __syncthreads();
        // maps tile (y0-1..y0+4) x (-1..64)
        const float* mp = maps + (size_t)((n*TT + t)*2) * HW;
        for (int idx = tid; idx < 2*6*66; idx += 256){
            int which = idx / 396;
            int r  = idx % 396;
            int yy = r / 66;
            int xx = r % 66;
            int gy = y0 - 1 + yy;
            int gx = xx - 1;
            float v = 0.f;
            if (gy >= 0 && gy < HH && gx >= 0 && gx < WW)
                v = mp[which*HW + gy*WW + gx];
            lm[idx] = v;
        }
        __syncthreads();
        // a/b tile (c0-1..c0+4) x (y0-1..y0+4) x (-1..64)
        const float* xp = x + (size_t)((n*TT + t)*CC) * HW;
        for (int idx = tid; idx < 6*6*66; idx += 256){
            int cc = idx / 396;
            int r  = idx % 396;
            int yy = r / 66;
            int xx = r % 66;
            int gc = c0 - 1 + cc;
            int gy = y0 - 1 + yy;
            int gx = xx - 1;
            float av = 0.f, bv = 0.f;
            if (gc >= 0 && gc < CC && gy >= 0 && gy < HH && gx >= 0 && gx < WW){
                float xv = xp[gc*HW + gy*WW + gx];
                float ip = imp[t*CC + gc];
                float fa = ip * xv;          // im_feat
                float fb = xv - fa;          // sub_feat
                av = fa * lm[r];             // * im_map
                bv = fb * lm[396 + r];       // * sub_map
            }
            la[idx] = av;
            lb[idx] = bv;
        }
        __syncthreads();
        // accumulate 27 taps
        for (int kd = 0; kd < 3; ++kd){
            for (int kh = 0; kh < 3; ++kh){
                #pragma unroll
                for (int kw = 0; kw < 3; ++kw){
                    int tap  = (kd*3 + kh)*3 + kw;
                    int woff = (t*27 + tap)*8;
                    float w1v[8], w2v[8];
                    #pragma unroll
                    for (int o = 0; o < 8; ++o){
                        w1v[o] = wl[woff + o];
                        w2v[o] = wl[1728 + woff + o];
                    }
                    #pragma unroll
                    for (int cl = 0; cl < CT; ++cl){
                        int li = ((cl+kd)*6 + (yl+kh))*66 + (xl+kw);
                        float av = la[li];
                        float bv = lb[li];
                        #pragma unroll
                        for (int o = 0; o < 8; ++o)
                            acc[o][cl] = fmaf(w1v[o], av, fmaf(w2v[o], bv, acc[o][cl]));
                    }
                }
            }
        }
    }
    // store (coalesced 256B per wave)
    int y = y0 + yl;
    #pragma unroll
    for (int o = 0; o < 8; ++o)
        #pragma unroll
        for (int cl = 0; cl < CT; ++cl){
            int c = c0 + cl;
            size_t oi = ((size_t)(n*TT + o)*CC + c)*HW + y*WW + xl;
            out[oi] = acc[o][cl];
        }
}

extern "C" void kernel_launch(void* const* d_in, const int* in_sizes, int n_in,
                              void* d_out, int out_size, void* d_ws, size_t ws_size,
                              hipStream_t stream){
    const float* x     = (const float*)d_in[0];   // (8,8,128,64,64) fp32
    const float* w1    = (const float*)d_in[1];   // (1,2,3,3)
    const float* w2    = (const float*)d_in[2];   // (1,2,3,3)
    const float* wlast = (const float*)d_in[3];   // (8,16,3,3,3)
    float* out = (float*)d_out;

    float* ws   = (float*)d_ws;
    float* M    = ws;               // 8192 floats
    float* imp  = ws + 8192;        // 1024 floats
    float* maps = ws + 9216;        // (8,8,2,4096) = 524288 floats

    k1_M      <<<dim3(NN*TT*CC), dim3(64),  0, stream>>>(x, M);
    k2_imp    <<<dim3(TT),       dim3(CC),  0, stream>>>(M, imp);
    k3_maps   <<<dim3(NN*TT),    dim3(512), 0, stream>>>(x, imp, w1, w2, maps);
    k5_conv3d <<<dim3(CC/CT, HH/YT, NN), dim3(256), 0, stream>>>(x, imp, wlast, maps, out);
}

// Round 3
// 468.596 us; speedup vs baseline: 1.6777x; 1.6777x over previous
//
#include <hip/hip_runtime.h>
#include <math.h>

#define NN 8
#define TT 8
#define CC 128
#define HH 64
#define WW 64
#define HW 4096

typedef unsigned int u32;
typedef unsigned short u16;
typedef __attribute__((ext_vector_type(8))) short short8;
typedef __attribute__((ext_vector_type(4))) float floatx4;

__device__ __forceinline__ u16 f2bf(float f){
    u32 u = __float_as_uint(f);
    u32 r = (u + 0x7fffu + ((u >> 16) & 1u)) >> 16;   // RNE
    return (u16)r;
}
__device__ __forceinline__ float bf2f(u16 h){
    return __uint_as_float(((u32)h) << 16);
}

// ---------------- K1: M[n,t,c] = mean_hw(x) + max_hw(x) -------------------
// 4 waves per block, one wave per (n,t,c) plane of 4096 fp32 elements
__global__ __launch_bounds__(256) void k1_M(const float* __restrict__ x, float* __restrict__ M){
    int plane = blockIdx.x * 4 + (threadIdx.x >> 6);
    int lane  = threadIdx.x & 63;
    const float* p = x + (size_t)plane * HW;
    float s = 0.f, mx = -INFINITY;
    #pragma unroll
    for (int it = 0; it < 16; ++it){
        float4 v = *(const float4*)(p + it*256 + lane*4);
        s += v.x + v.y + v.z + v.w;
        mx = fmaxf(mx, fmaxf(fmaxf(v.x, v.y), fmaxf(v.z, v.w)));
    }
    #pragma unroll
    for (int off = 32; off > 0; off >>= 1){
        s += __shfl_xor(s, off, 64);
        mx = fmaxf(mx, __shfl_xor(mx, off, 64));
    }
    if (lane == 0) M[plane] = s * (1.0f/(float)HW) + mx;
}

// ---------------- K2: imp[t,c] = XOR of unioned top-k masks ---------------
__global__ __launch_bounds__(128) void k2_imp(const float* __restrict__ M, float* __restrict__ imp){
    int t = blockIdx.x;       // 0..7
    int c = threadIdx.x;      // 0..127
    __shared__ float Ms[NN*CC];
    for (int n = 0; n < NN; ++n)
        Ms[n*CC + c] = M[(n*TT + t)*CC + c];
    __syncthreads();
    bool sel_ch = false;
    for (int n = 0; n < NN; ++n){
        float mv = Ms[n*CC + c];
        int rank = 0;
        for (int c2 = 0; c2 < CC; ++c2){
            float v2 = Ms[n*CC + c2];
            rank += (v2 > mv) || (v2 == mv && c2 < c);
        }
        sel_ch = sel_ch || (rank < 64);   // kc = 64
    }
    bool sel_tm = false;
    for (int n = 0; n < NN; ++n){
        float mv = M[(n*TT + t)*CC + c];
        int rank = 0;
        for (int t2 = 0; t2 < TT; ++t2){
            float v2 = M[(n*TT + t2)*CC + c];
            rank += (v2 > mv) || (v2 == mv && t2 < t);
        }
        sel_tm = sel_tm || (rank < 4);    // kt = 4
    }
    imp[t*CC + c] = (sel_ch != sel_tm) ? 1.0f : 0.0f;
}

// ---------------- K3a: channel stats (bf16 out) ---------------------------
// grid (64, 8): one thread per pixel, loop over 128 channels
__global__ __launch_bounds__(512) void k3a_stats(const float* __restrict__ x,
        const float* __restrict__ imp, u16* __restrict__ st){
    int nt = blockIdx.x; int t = nt & 7;
    int px = blockIdx.y * 512 + threadIdx.x;
    const float* xp = x + (size_t)nt * CC * HW + px;
    float sa = 0.f, sb = 0.f, ma = -INFINITY, mb = -INFINITY;
    for (int c = 0; c < CC; ++c){
        float ip = imp[t*CC + c];
        float v = xp[c*HW];
        float a = ip*v, b = v - a;
        sa += a; sb += b;
        ma = fmaxf(ma, a); mb = fmaxf(mb, b);
    }
    st[(nt*4+0)*HW + px] = f2bf(sa * (1.f/64.f));   // mean/128/0.5
    st[(nt*4+1)*HW + px] = f2bf(ma);
    st[(nt*4+2)*HW + px] = f2bf(sb * (1.f/64.f));
    st[(nt*4+3)*HW + px] = f2bf(mb);
}

// ---------------- K3b: 3x3 conv + sigmoid -> maps -------------------------
// grid (64, 4): each block does 16 y-rows
__global__ __launch_bounds__(256) void k3b_maps(const u16* __restrict__ st,
        const float* __restrict__ w1, const float* __restrict__ w2,
        float* __restrict__ maps){
    int nt = blockIdx.x;
    int y0 = blockIdx.y * 16;
    __shared__ float S[4*18*66];
    int tid = threadIdx.x;
    for (int idx = tid; idx < 4*18*66; idx += 256){
        int s  = idx / 1188;
        int r  = (idx % 1188) / 66;
        int xx = idx % 66;
        int gy = y0 - 1 + r, gx = xx - 1;
        float v = 0.f;
        if ((u32)gy < HH && (u32)gx < WW)
            v = bf2f(st[(nt*4 + s)*HW + gy*WW + gx]);
        S[idx] = v;
    }
    __syncthreads();
    float wa[18], wb[18];
    #pragma unroll
    for (int i = 0; i < 18; ++i){ wa[i] = w1[i]; wb[i] = w2[i]; }
    for (int k = 0; k < 4; ++k){
        int p = k*256 + tid;
        int y = p >> 6, xx = p & 63;
        float zi = 0.f, zs = 0.f;
        #pragma unroll
        for (int dy = 0; dy < 3; ++dy)
            #pragma unroll
            for (int dx = 0; dx < 3; ++dx){
                int sp = (y+dy)*66 + xx + dx;
                zi += wa[dy*3+dx] * S[sp] + wa[9+dy*3+dx] * S[1188 + sp];
                zs += wb[dy*3+dx] * S[2376 + sp] + wb[9+dy*3+dx] * S[3564 + sp];
            }
        maps[(nt*2+0)*HW + y0*WW + p] = 1.0f / (1.0f + expf(-zi));
        maps[(nt*2+1)*HW + y0*WW + p] = 1.0f / (1.0f + expf(-zs));
    }
}

// ---------------- K5: MFMA fused 3D conv ----------------------------------
// mfma_f32_16x16x32_bf16: M=16 -> o (8 real), N=16 -> x pixels,
// K=32 -> 16 channels (a:t0-7, b:t0-7) x tap pair. 14 steps cover 27 taps+pad.
// LDS: feat[pixel][16ch] bf16, pixel = (c''*6+y'')*66+x'' over (CT+2=4, YT+2=6, 66)
constexpr int offb(int tap){
    return (((tap/9)*6 + ((tap/3)%3))*66 + (tap%3))*32;
}

__global__ __launch_bounds__(256) void k5_conv3d(
        const float* __restrict__ x, const float* __restrict__ impg,
        const float* __restrict__ wlast, const float* __restrict__ maps,
        float* __restrict__ out){
    __shared__ __align__(16) u16 feat[1584*16];   // 50,688 B
    __shared__ float impl[TT*CC];                 // 4 KB
    int tid  = threadIdx.x;
    int lane = tid & 63;
    int w    = tid >> 6;
    int c0 = blockIdx.x * 2;
    int y0 = blockIdx.y * 4;
    int n  = blockIdx.z;

    for (int idx = tid; idx < TT*CC; idx += 256) impl[idx] = impg[idx];

    // ---- build A-fragments (weights) in LDS scratch, then load to regs ----
    // record (step*64+l): lane l holds A[m=l&15][k=(l>>4)*8+j]
    // k -> (s = k>>4, i = k&15); tap = 2*step + s; value = W[o=m][i][tap]
    for (int idx = tid; idx < 896; idx += 256){
        int stp = idx >> 6;
        int l   = idx & 63;
        int m = l & 15, q = l >> 4;
        int i0 = (q & 1) * 8, s = q >> 1;
        int tap = 2*stp + s;
        bool valid = (m < 8) && (tap < 27);
        union { u16 h[8]; uint4 v; } pk;
        #pragma unroll
        for (int j = 0; j < 8; ++j){
            float wv = valid ? wlast[(m*16 + i0 + j)*27 + tap] : 0.f;
            pk.h[j] = f2bf(wv);
        }
        *(uint4*)(feat + idx*8) = pk.v;
    }
    __syncthreads();
    short8 afr[14];
    #pragma unroll
    for (int stp = 0; stp < 14; ++stp)
        afr[stp] = *(const short8*)(feat + (stp*64 + lane)*8);
    __syncthreads();

    // ---- stage feature tile: a = imp*x*im_map, b = (1-imp)*x*sub_map ------
    const float* xn  = x    + (size_t)n * TT * CC * HW;
    const float* mpn = maps + (size_t)n * TT * 2 * HW;
    for (int idx = tid; idx < 1584; idx += 256){
        int cc  = idx / 396;          // 0..3
        int rm  = idx % 396;
        int yyl = rm / 66;            // 0..5
        int xx  = rm % 66;            // 0..65
        int gc = c0 - 1 + cc;
        int gy = y0 - 1 + yyl;
        int gx = xx - 1;
        union { u16 h[16]; uint4 v[2]; } r;
        if ((u32)gc < CC && (u32)gy < HH && (u32)gx < WW){
            int gp = gy*WW + gx;
            #pragma unroll
            for (int t = 0; t < TT; ++t){
                float xv = xn[((size_t)t*CC + gc)*HW + gp];
                float ip = impl[t*CC + gc];
                float a  = ip * xv;
                float av = a * mpn[(t*2+0)*HW + gp];
                float bv = (xv - a) * mpn[(t*2+1)*HW + gp];
                r.h[t]   = f2bf(av);
                r.h[8+t] = f2bf(bv);
            }
        } else {
            r.v[0] = make_uint4(0,0,0,0);
            r.v[1] = make_uint4(0,0,0,0);
        }
        *(uint4*)(feat + idx*16)     = r.v[0];
        *(uint4*)(feat + idx*16 + 8) = r.v[1];
    }
    __syncthreads();

    // ---- MFMA main: wave w -> cl = w&1, yl in {2*(w>>1), +1}, 4 x-groups --
    int col = lane & 15;
    int hi  = (lane >> 4) & 1;        // which 8-channel half
    int s   = lane >> 5;              // which tap of the pair
    int offs[14];
    #pragma unroll
    for (int stp = 0; stp < 14; ++stp){
        int o0 = offb(2*stp);
        int o1 = offb(2*stp+1 < 27 ? 2*stp+1 : 0);  // pad tap -> safe addr, zero A
        offs[stp] = s ? o1 : o0;
    }
    int cl = w & 1;
    const char* fbase = (const char*)feat;
    for (int yy = 0; yy < 2; ++yy){
        int yl = (w >> 1)*2 + yy;
        int rowb = ((cl*6 + yl)*66 + col)*32 + hi*16;
        #pragma unroll
        for (int xp = 0; xp < 2; ++xp){
            int b0off = rowb + xp*1024;       // xg0 = 2*xp -> 32 px * 32 B
            int b1off = b0off + 512;          // +16 px
            floatx4 acc0 = {0.f,0.f,0.f,0.f};
            floatx4 acc1 = {0.f,0.f,0.f,0.f};
            #pragma unroll
            for (int stp = 0; stp < 14; ++stp){
                short8 b0 = *(const short8*)(fbase + b0off + offs[stp]);
                short8 b1 = *(const short8*)(fbase + b1off + offs[stp]);
                acc0 = __builtin_amdgcn_mfma_f32_16x16x32_bf16(afr[stp], b0, acc0, 0, 0, 0);
                acc1 = __builtin_amdgcn_mfma_f32_16x16x32_bf16(afr[stp], b1, acc1, 0, 0, 0);
            }
            // C/D: col = lane&15, row = (lane>>4)*4 + reg; rows 8..15 are pad
            if (lane < 32){
                int c = c0 + cl, y = y0 + yl;
                int xa = xp*32 + col;
                #pragma unroll
                for (int rg = 0; rg < 4; ++rg){
                    int o = (lane >> 4)*4 + rg;
                    size_t ob = (((size_t)(n*TT + o))*CC + c)*HW + y*WW;
                    out[ob + xa]      = acc0[rg];
                    out[ob + xa + 16] = acc1[rg];
                }
            }
        }
    }
}

extern "C" void kernel_launch(void* const* d_in, const int* in_sizes, int n_in,
                              void* d_out, int out_size, void* d_ws, size_t ws_size,
                              hipStream_t stream){
    const float* x     = (const float*)d_in[0];   // (8,8,128,64,64) fp32
    const float* w1    = (const float*)d_in[1];   // (1,2,3,3)
    const float* w2    = (const float*)d_in[2];   // (1,2,3,3)
    const float* wlast = (const float*)d_in[3];   // (8,16,3,3,3)
    float* out = (float*)d_out;

    float* ws   = (float*)d_ws;
    float* M    = ws;                  // 8,192 f32
    float* imp  = ws + 8192;           // 1,024 f32
    float* maps = ws + 9216;           // 524,288 f32
    u16*   st   = (u16*)(ws + 9216 + 524288);   // 1,048,576 bf16 (2 MB)
    // total ws: ~4.24 MB

    k1_M      <<<dim3(NN*TT*CC/4), dim3(256), 0, stream>>>(x, M);
    k2_imp    <<<dim3(TT),         dim3(128), 0, stream>>>(M, imp);
    k3a_stats <<<dim3(NN*TT, 8),   dim3(512), 0, stream>>>(x, imp, st);
    k3b_maps  <<<dim3(NN*TT, 4),   dim3(256), 0, stream>>>(st, w1, w2, maps);
    k5_conv3d <<<dim3(CC/2, HH/4, NN), dim3(256), 0, stream>>>(x, imp, wlast, maps, out);
}

// Round 4
// 440.238 us; speedup vs baseline: 1.7858x; 1.0644x over previous
//
#include <hip/hip_runtime.h>
#include <math.h>

#define NN 8
#define TT 8
#define CC 128
#define HH 64
#define WW 64
#define HW 4096

typedef unsigned int u32;
typedef unsigned short u16;
typedef __attribute__((ext_vector_type(8))) short short8;
typedef __attribute__((ext_vector_type(4))) float floatx4;

__device__ __forceinline__ u16 f2bf(float f){
    u32 u = __float_as_uint(f);
    u32 r = (u + 0x7fffu + ((u >> 16) & 1u)) >> 16;   // RNE
    return (u16)r;
}
__device__ __forceinline__ float bf2f(u16 h){
    return __uint_as_float(((u32)h) << 16);
}

// ---------------- K1: M[n,t,c] = mean_hw(x) + max_hw(x) -------------------
__global__ __launch_bounds__(256) void k1_M(const float* __restrict__ x, float* __restrict__ M){
    int plane = blockIdx.x * 4 + (threadIdx.x >> 6);
    int lane  = threadIdx.x & 63;
    const float* p = x + (size_t)plane * HW;
    float s = 0.f, mx = -INFINITY;
    #pragma unroll
    for (int it = 0; it < 16; ++it){
        float4 v = *(const float4*)(p + it*256 + lane*4);
        s += v.x + v.y + v.z + v.w;
        mx = fmaxf(mx, fmaxf(fmaxf(v.x, v.y), fmaxf(v.z, v.w)));
    }
    #pragma unroll
    for (int off = 32; off > 0; off >>= 1){
        s += __shfl_xor(s, off, 64);
        mx = fmaxf(mx, __shfl_xor(mx, off, 64));
    }
    if (lane == 0) M[plane] = s * (1.0f/(float)HW) + mx;
}

// ---------------- K2: imp[t,c] = XOR of unioned top-k masks ---------------
__global__ __launch_bounds__(128) void k2_imp(const float* __restrict__ M, float* __restrict__ imp){
    int t = blockIdx.x;       // 0..7
    int c = threadIdx.x;      // 0..127
    __shared__ float Ms[NN*CC];
    for (int n = 0; n < NN; ++n)
        Ms[n*CC + c] = M[(n*TT + t)*CC + c];
    __syncthreads();
    bool sel_ch = false;
    for (int n = 0; n < NN; ++n){
        float mv = Ms[n*CC + c];
        int rank = 0;
        for (int c2 = 0; c2 < CC; ++c2){
            float v2 = Ms[n*CC + c2];
            rank += (v2 > mv) || (v2 == mv && c2 < c);
        }
        sel_ch = sel_ch || (rank < 64);   // kc = 64
    }
    bool sel_tm = false;
    for (int n = 0; n < NN; ++n){
        float mv = M[(n*TT + t)*CC + c];
        int rank = 0;
        for (int t2 = 0; t2 < TT; ++t2){
            float v2 = M[(n*TT + t2)*CC + c];
            rank += (v2 > mv) || (v2 == mv && t2 < t);
        }
        sel_tm = sel_tm || (rank < 4);    // kt = 4
    }
    imp[t*CC + c] = (sel_ch != sel_tm) ? 1.0f : 0.0f;
}

// ---------------- K3a: channel stats (bf16 out) ---------------------------
__global__ __launch_bounds__(512) void k3a_stats(const float* __restrict__ x,
        const float* __restrict__ imp, u16* __restrict__ st){
    int nt = blockIdx.x; int t = nt & 7;
    int px = blockIdx.y * 512 + threadIdx.x;
    const float* xp = x + (size_t)nt * CC * HW + px;
    float sa = 0.f, sb = 0.f, ma = -INFINITY, mb = -INFINITY;
    for (int c = 0; c < CC; ++c){
        float ip = imp[t*CC + c];
        float v = xp[c*HW];
        float a = ip*v, b = v - a;
        sa += a; sb += b;
        ma = fmaxf(ma, a); mb = fmaxf(mb, b);
    }
    st[(nt*4+0)*HW + px] = f2bf(sa * (1.f/64.f));   // mean/128/0.5
    st[(nt*4+1)*HW + px] = f2bf(ma);
    st[(nt*4+2)*HW + px] = f2bf(sb * (1.f/64.f));
    st[(nt*4+3)*HW + px] = f2bf(mb);
}

// ---------------- K3b: 3x3 conv + sigmoid -> maps -------------------------
__global__ __launch_bounds__(256) void k3b_maps(const u16* __restrict__ st,
        const float* __restrict__ w1, const float* __restrict__ w2,
        float* __restrict__ maps){
    int nt = blockIdx.x;
    int y0 = blockIdx.y * 16;
    __shared__ float S[4*18*66];
    int tid = threadIdx.x;
    for (int idx = tid; idx < 4*18*66; idx += 256){
        int s  = idx / 1188;
        int r  = (idx % 1188) / 66;
        int xx = idx % 66;
        int gy = y0 - 1 + r, gx = xx - 1;
        float v = 0.f;
        if ((u32)gy < HH && (u32)gx < WW)
            v = bf2f(st[(nt*4 + s)*HW + gy*WW + gx]);
        S[idx] = v;
    }
    __syncthreads();
    float wa[18], wb[18];
    #pragma unroll
    for (int i = 0; i < 18; ++i){ wa[i] = w1[i]; wb[i] = w2[i]; }
    for (int k = 0; k < 4; ++k){
        int p = k*256 + tid;
        int y = p >> 6, xx = p & 63;
        float zi = 0.f, zs = 0.f;
        #pragma unroll
        for (int dy = 0; dy < 3; ++dy)
            #pragma unroll
            for (int dx = 0; dx < 3; ++dx){
                int sp = (y+dy)*66 + xx + dx;
                zi += wa[dy*3+dx] * S[sp] + wa[9+dy*3+dx] * S[1188 + sp];
                zs += wb[dy*3+dx] * S[2376 + sp] + wb[9+dy*3+dx] * S[3564 + sp];
            }
        maps[(nt*2+0)*HW + y0*WW + p] = 1.0f / (1.0f + expf(-zi));
        maps[(nt*2+1)*HW + y0*WW + p] = 1.0f / (1.0f + expf(-zs));
    }
}

// ---------------- K4: xs[n][c][p][t] = bf16( x * (imp? im_map : sub_map) ) -
// one block per (c, n); coalesced reads of 8 t-planes, b128 record writes
__global__ __launch_bounds__(256) void k4_xs(const float* __restrict__ x,
        const float* __restrict__ impf, const float* __restrict__ maps,
        u16* __restrict__ xs){
    int c = blockIdx.x;      // 0..127
    int n = blockIdx.y;      // 0..7
    int tid = threadIdx.x;
    const float* mp[TT];
    #pragma unroll
    for (int t = 0; t < TT; ++t){
        float v = impf[t*CC + c];
        mp[t] = maps + ((size_t)((n*TT + t)*2) + (v > 0.f ? 0 : 1)) * HW;
    }
    const float* xb = x + ((size_t)(n*TT)*CC + c) * HW;
    u16* xr = xs + ((size_t)n*CC + c) * HW * 8;
    for (int it = 0; it < 16; ++it){
        int p = it*256 + tid;
        union { u16 h[8]; uint4 v4; } r;
        #pragma unroll
        for (int t = 0; t < TT; ++t){
            float xv = xb[(size_t)t*CC*HW + p];
            r.h[t] = f2bf(xv * mp[t][p]);
        }
        *(uint4*)(xr + (size_t)p*8) = r.v4;
    }
}

// ---------------- K5: MFMA fused 3D conv ----------------------------------
// mfma_f32_16x16x32_bf16: M=16 -> o (8 real), N=16 -> x pixels,
// K=32 -> 16 channels (im t0-7, sub t0-7) x tap pair (14 steps, 27 taps + pad)
// LDS: fim/fsb[pixel][8ch] bf16 16-B records -> conflict-free b128 r/w
constexpr int offb16(int tap){
    return (((tap/9)*6 + ((tap/3)%3))*66 + (tap%3))*16;
}

template<bool USE_XS>
__global__ __launch_bounds__(256) void k5_conv3d(
        const float* __restrict__ x, const u16* __restrict__ xs,
        const float* __restrict__ impf, const float* __restrict__ wlast,
        const float* __restrict__ maps, float* __restrict__ out){
    __shared__ __align__(16) u16 fim[1584*8];    // 25,344 B
    __shared__ __align__(16) u16 fsb[1584*8];    // 25,344 B
    __shared__ u32 maskw[CC*4];                  //  2,048 B
    int tid  = threadIdx.x;
    int lane = tid & 63;
    int w    = tid >> 6;
    int c0 = blockIdx.x * 2;
    int y0 = blockIdx.y * 4;
    int n  = blockIdx.z;

    // ---- masks: maskw[c*4+j] covers t-pair (2j,2j+1) ----------------------
    for (int idx = tid; idx < CC*4; idx += 256){
        int c = idx >> 2, j = idx & 3;
        u32 m = (impf[(2*j)*CC + c]   > 0.f ? 0x0000FFFFu : 0u)
              | (impf[(2*j+1)*CC + c] > 0.f ? 0xFFFF0000u : 0u);
        maskw[idx] = m;
    }

    // ---- build A-fragments (weights) in fim scratch, load to regs ---------
    for (int idx = tid; idx < 896; idx += 256){
        int stp = idx >> 6;
        int l   = idx & 63;
        int m = l & 15, q = l >> 4;
        int i0 = (q & 1) * 8, s = q >> 1;
        int tap = 2*stp + s;
        bool valid = (m < 8) && (tap < 27);
        union { u16 h[8]; uint4 v; } pk;
        #pragma unroll
        for (int j = 0; j < 8; ++j){
            float wv = valid ? wlast[(m*16 + i0 + j)*27 + tap] : 0.f;
            pk.h[j] = f2bf(wv);
        }
        *(uint4*)(fim + idx*8) = pk.v;
    }
    __syncthreads();
    short8 afr[14];
    #pragma unroll
    for (int stp = 0; stp < 14; ++stp)
        afr[stp] = *(const short8*)(fim + (stp*64 + lane)*8);
    __syncthreads();

    // ---- stage feature tile (4c x 6y x 66x) -------------------------------
    for (int idx = tid; idx < 1584; idx += 256){
        int cc  = idx / 396;
        int rm  = idx % 396;
        int yyl = rm / 66;
        int xx  = rm % 66;
        int gc = c0 - 1 + cc;
        int gy = y0 - 1 + yyl;
        int gx = xx - 1;
        uint4 vim = make_uint4(0,0,0,0), vsb = make_uint4(0,0,0,0);
        if ((u32)gc < CC && (u32)gy < HH && (u32)gx < WW){
            int gp = gy*WW + gx;
            u32 al[4];
            if (USE_XS){
                uint4 v = *(const uint4*)(xs + (((size_t)n*CC + gc)*HW + gp)*8);
                al[0] = v.x; al[1] = v.y; al[2] = v.z; al[3] = v.w;
            } else {
                const float* xn  = x    + (((size_t)n*TT)*CC + gc)*HW + gp;
                const float* mpn = maps + ((size_t)n*TT*2)*HW + gp;
                u16 hv[8];
                #pragma unroll
                for (int t = 0; t < TT; ++t){
                    float ip = impf[t*CC + gc];
                    float xv = xn[(size_t)t*CC*HW];
                    float mv = mpn[((size_t)t*2 + (ip > 0.f ? 0 : 1))*HW];
                    hv[t] = f2bf(xv * mv);
                }
                #pragma unroll
                for (int j = 0; j < 4; ++j)
                    al[j] = (u32)hv[2*j] | ((u32)hv[2*j+1] << 16);
            }
            u32 m0 = maskw[gc*4+0], m1 = maskw[gc*4+1];
            u32 m2 = maskw[gc*4+2], m3 = maskw[gc*4+3];
            vim.x = al[0] & m0; vim.y = al[1] & m1;
            vim.z = al[2] & m2; vim.w = al[3] & m3;
            vsb.x = al[0] ^ vim.x; vsb.y = al[1] ^ vim.y;
            vsb.z = al[2] ^ vim.z; vsb.w = al[3] ^ vim.w;
        }
        *(uint4*)(fim + idx*8) = vim;
        *(uint4*)(fsb + idx*8) = vsb;
    }
    __syncthreads();

    // ---- MFMA main --------------------------------------------------------
    int col = lane & 15;
    int q   = (lane >> 4) & 1;        // im vs sub half
    int s   = lane >> 5;              // tap of the pair
    const char* fb = (const char*)(q ? fsb : fim);
    int offs[14];
    #pragma unroll
    for (int stp = 0; stp < 14; ++stp){
        int tap = 2*stp + s;
        if (tap >= 27) tap = 0;       // pad tap: safe addr, A is zero there
        offs[stp] = offb16(tap);
    }
    int cl = w & 1;
    for (int yy = 0; yy < 2; ++yy){
        int yl = (w >> 1)*2 + yy;
        int rowb = ((cl*6 + yl)*66 + col)*16;
        #pragma unroll
        for (int xp = 0; xp < 2; ++xp){
            int b0off = rowb + xp*512;        // 32 px * 16 B
            int b1off = b0off + 256;          // +16 px
            floatx4 acc0 = {0.f,0.f,0.f,0.f};
            floatx4 acc1 = {0.f,0.f,0.f,0.f};
            #pragma unroll
            for (int stp = 0; stp < 14; ++stp){
                short8 b0 = *(const short8*)(fb + b0off + offs[stp]);
                short8 b1 = *(const short8*)(fb + b1off + offs[stp]);
                acc0 = __builtin_amdgcn_mfma_f32_16x16x32_bf16(afr[stp], b0, acc0, 0, 0, 0);
                acc1 = __builtin_amdgcn_mfma_f32_16x16x32_bf16(afr[stp], b1, acc1, 0, 0, 0);
            }
            // C/D: col = lane&15, row = (lane>>4)*4 + reg; rows 8..15 pad
            if (lane < 32){
                int c = c0 + cl, y = y0 + yl;
                int xa = xp*32 + col;
                #pragma unroll
                for (int rg = 0; rg < 4; ++rg){
                    int o = (lane >> 4)*4 + rg;
                    size_t ob = (((size_t)(n*TT + o))*CC + c)*HW + y*WW;
                    out[ob + xa]      = acc0[rg];
                    out[ob + xa + 16] = acc1[rg];
                }
            }
        }
    }
}

extern "C" void kernel_launch(void* const* d_in, const int* in_sizes, int n_in,
                              void* d_out, int out_size, void* d_ws, size_t ws_size,
                              hipStream_t stream){
    const float* x     = (const float*)d_in[0];   // (8,8,128,64,64) fp32
    const float* w1    = (const float*)d_in[1];   // (1,2,3,3)
    const float* w2    = (const float*)d_in[2];   // (1,2,3,3)
    const float* wlast = (const float*)d_in[3];   // (8,16,3,3,3)
    float* out = (float*)d_out;

    float* ws   = (float*)d_ws;
    float* M    = ws;                           // 8,192 f32
    float* imp  = ws + 8192;                    // 1,024 f32
    float* maps = ws + 9216;                    // 524,288 f32
    u16*   st   = (u16*)(ws + 9216 + 524288);   // 1,048,576 u16 (2 MB)
    u16*   xs   = (u16*)(ws + 9216 + 524288 + 524288);  // 67,108,864 B
    const size_t WS_NEED = (size_t)(9216 + 524288 + 524288) * 4 + (size_t)NN*TT*CC*HW*2;

    k1_M      <<<dim3(NN*TT*CC/4), dim3(256), 0, stream>>>(x, M);
    k2_imp    <<<dim3(TT),         dim3(128), 0, stream>>>(M, imp);
    k3a_stats <<<dim3(NN*TT, 8),   dim3(512), 0, stream>>>(x, imp, st);
    k3b_maps  <<<dim3(NN*TT, 4),   dim3(256), 0, stream>>>(st, w1, w2, maps);
    if (ws_size >= WS_NEED){
        k4_xs <<<dim3(CC, NN), dim3(256), 0, stream>>>(x, imp, maps, xs);
        k5_conv3d<true>  <<<dim3(CC/2, HH/4, NN), dim3(256), 0, stream>>>(x, xs, imp, wlast, maps, out);
    } else {
        k5_conv3d<false> <<<dim3(CC/2, HH/4, NN), dim3(256), 0, stream>>>(x, xs, imp, wlast, maps, out);
    }
}